// Round 6
// baseline (443.086 us; speedup 1.0000x reference)
//
#include <hip/hip_runtime.h>

// VQ: z [32,256,32,32] f32, codebook [1024,256] f32
// out: z_q [32,256,32,32] f32 (8388608) then loss scalar f32 (1)
#define NELEM 8388608

typedef __attribute__((ext_vector_type(16))) float f32x16;
typedef unsigned long long ull;

// ---------------------------------------------------------------------------
// prep: codebook -> fp8 e4m3 (scaled x256, exact pow2) in B-fragment-linear
// order for mfma_f32_32x32x16_fp8_fp8, plus exact fp32 norms cn[k].
// frag g = nt*16+ks (512 B): lane L holds cb[nt*32+(L&31)][ks*16+(L>>5)*8+0..7]
__global__ __launch_bounds__(256) void prep_kernel(const float* __restrict__ cb,
                                                   uint2* __restrict__ cbf8,
                                                   float* __restrict__ cn) {
    const int t = threadIdx.x;
    const int gt = blockIdx.x * 256 + t;          // 0..32767
    const int L = gt & 63, g = gt >> 6;           // frag 0..511
    const int nt = g >> 4, ks = g & 15;
    const int code = nt * 32 + (L & 31);
    const int k0 = ks * 16 + (L >> 5) * 8;
    const float* s = cb + code * 256 + k0;
    float v[8];
    #pragma unroll
    for (int j = 0; j < 8; ++j) v[j] = s[j] * 256.0f;
    int lo = 0, hi = 0;
    lo = __builtin_amdgcn_cvt_pk_fp8_f32(v[0], v[1], lo, false);
    lo = __builtin_amdgcn_cvt_pk_fp8_f32(v[2], v[3], lo, true);
    hi = __builtin_amdgcn_cvt_pk_fp8_f32(v[4], v[5], hi, false);
    hi = __builtin_amdgcn_cvt_pk_fp8_f32(v[6], v[7], hi, true);
    uint2 o; o.x = (unsigned)lo; o.y = (unsigned)hi;
    cbf8[g * 64 + L] = o;

    const int w = t >> 6, lane = t & 63;
    #pragma unroll
    for (int cc = 0; cc < 2; ++cc) {
        int cd = blockIdx.x * 8 + w * 2 + cc;
        float4 qv = *(const float4*)(cb + cd * 256 + lane * 4);
        float s2 = qv.x*qv.x + qv.y*qv.y + qv.z*qv.z + qv.w*qv.w;
        #pragma unroll
        for (int off = 32; off; off >>= 1) s2 += __shfl_down(s2, off, 64);
        if (lane == 0) cn[cd] = s2;
    }
}

// ---------------------------------------------------------------------------
// Argmin: grid 512 = 256 pos-groups x 2 codebook-halves. Block 256 thr =
// 4 waves x 32 pos = 128 pos, 512 codes. No LDS, no barriers; A resident in
// regs, B-frags streamed global->reg (L1/L2 hot), 32x32x16 fp8 MFMA.
// d = (cn[k]+1) - 2*dot > 0  =>  float bits monotone; key = (bits&~1023)|code.
// Each half writes its own keys slot (no atomics); scatter min-combines.
__global__ __launch_bounds__(256, 2) void vq_kernel(
        const float* __restrict__ z, const uint2* __restrict__ cbf8,
        const float* __restrict__ cn, unsigned* __restrict__ keys) {
    const int t = threadIdx.x, w = t >> 6, L = t & 63;
    const int half = blockIdx.x >> 8;             // pairs 256 apart: same XCD
    const int pg = blockIdx.x & 255;
    const int b = pg >> 3, hw0 = (pg & 7) << 7;
    const int m = L & 31, hf = L >> 5;

    // A-frags: wave w owns pos w*32..w*32+31. A[m][k=ks*16+hf*8+j], x16 -> fp8
    ull af[16];
    const float* zb = z + ((size_t)b << 18) + hw0 + w * 32 + m;
    #pragma unroll
    for (int ks = 0; ks < 16; ++ks) {
        const float* sp = zb + ((size_t)(ks * 16 + hf * 8) << 10);
        float v[8];
        #pragma unroll
        for (int j = 0; j < 8; ++j) v[j] = sp[(size_t)j << 10];
        int lo = 0, hi = 0;
        lo = __builtin_amdgcn_cvt_pk_fp8_f32(v[0]*16.f, v[1]*16.f, lo, false);
        lo = __builtin_amdgcn_cvt_pk_fp8_f32(v[2]*16.f, v[3]*16.f, lo, true);
        hi = __builtin_amdgcn_cvt_pk_fp8_f32(v[4]*16.f, v[5]*16.f, hi, false);
        hi = __builtin_amdgcn_cvt_pk_fp8_f32(v[6]*16.f, v[7]*16.f, hi, true);
        af[ks] = ((ull)(unsigned)hi << 32) | (unsigned)lo;
    }

    const int colcode = half * 512 + m;
    float cnreg[16];
    #pragma unroll
    for (int nt = 0; nt < 16; ++nt) cnreg[nt] = cn[colcode + nt * 32] + 1.0f;

    unsigned runmin[16];
    #pragma unroll
    for (int r = 0; r < 16; ++r) runmin[r] = 0xFFFFFFFFu;

    const uint2* bp = cbf8 + (size_t)(half * 256) * 64;
    const float SC = -4.8828125e-4f;              // -2 / (16*256)

    uint2 cura[16], nxta[16];
    #pragma unroll
    for (int ks = 0; ks < 16; ++ks) cura[ks] = bp[ks * 64 + L];

    #pragma unroll
    for (int nt = 0; nt < 16; ++nt) {
        if (nt < 15) {
            #pragma unroll
            for (int ks = 0; ks < 16; ++ks)
                nxta[ks] = bp[((nt + 1) * 16 + ks) * 64 + L];
        }
        f32x16 acc = {0,0,0,0, 0,0,0,0, 0,0,0,0, 0,0,0,0};
        #pragma unroll
        for (int ks = 0; ks < 16; ++ks) {
            ull bb = ((ull)cura[ks].y << 32) | cura[ks].x;
            acc = __builtin_amdgcn_mfma_f32_32x32x16_fp8_fp8(
                      (long long)af[ks], (long long)bb, acc, 0, 0, 0);
        }
        const unsigned kc = (unsigned)(colcode + nt * 32);
        #pragma unroll
        for (int r = 0; r < 16; ++r) {
            float d = fmaf(SC, acc[r], cnreg[nt]);          // in [0.5, 1.5]
            unsigned key = (__float_as_uint(d) & 0xFFFFFC00u) | kc;
            runmin[r] = min(runmin[r], key);
        }
        if (nt < 15) {
            #pragma unroll
            for (int ks = 0; ks < 16; ++ks) cura[ks] = nxta[ks];
        }
    }

    // cross-lane min over 32 code columns (xor<32 stays within half-wave)
    #pragma unroll
    for (int r = 0; r < 16; ++r) {
        unsigned v = runmin[r];
        #pragma unroll
        for (int d = 1; d < 32; d <<= 1) v = min(v, (unsigned)__shfl_xor(v, d, 64));
        if (m == 0) {
            int row = (r & 3) + 8 * (r >> 2) + 4 * hf;
            keys[half * 32768 + pg * 128 + w * 32 + row] = v;
        }
    }
}

// ---------------------------------------------------------------------------
// Scatter: combine halves, gather fp32 codebook rows (coalesced), transpose
// via LDS, write z_q; exact loss = 1.25*mean((q-z)^2).
__global__ __launch_bounds__(256) void scatter_kernel(
        const float* __restrict__ z, const float* __restrict__ cb,
        const unsigned* __restrict__ keys, float* __restrict__ out,
        float* __restrict__ loss) {
    __shared__ float Q[32][257];
    __shared__ int codeS[64];
    __shared__ float wsum[4];
    const int t = threadIdx.x, w = t >> 6, L = t & 63;
    const int n0 = blockIdx.x * 64;
    const int b = n0 >> 10, hw0 = n0 & 1023;

    if (t < 64) codeS[t] = (int)(min(keys[n0 + t], keys[32768 + n0 + t]) & 1023u);
    __syncthreads();

    float acc = 0.f;
    const size_t obase = ((size_t)b << 18) + hw0;
    const int pgq = L & 7, cidx = L >> 3;
    #pragma unroll
    for (int ch = 0; ch < 2; ++ch) {
        if (ch) __syncthreads();
        #pragma unroll
        for (int rr = 0; rr < 8; ++rr) {
            int row = w * 8 + rr;
            int code = codeS[ch * 32 + row];
            float4 v = *(const float4*)(cb + ((size_t)code << 8) + (L << 2));
            float* qp = &Q[row][L << 2];
            qp[0] = v.x; qp[1] = v.y; qp[2] = v.z; qp[3] = v.w;
        }
        __syncthreads();
        #pragma unroll
        for (int i = 0; i < 8; ++i) {
            int c = w * 64 + i * 8 + cidx;
            int p0 = pgq * 4;
            float4 qv;
            qv.x = Q[p0 + 0][c]; qv.y = Q[p0 + 1][c];
            qv.z = Q[p0 + 2][c]; qv.w = Q[p0 + 3][c];
            size_t addr = obase + ((size_t)c << 10) + ch * 32 + p0;
            float4 zv = *(const float4*)(z + addr);
            *(float4*)(out + addr) = qv;
            float dx = qv.x - zv.x, dy = qv.y - zv.y;
            float dz2 = qv.z - zv.z, dw = qv.w - zv.w;
            acc += dx * dx + dy * dy + dz2 * dz2 + dw * dw;
        }
    }
    #pragma unroll
    for (int off = 32; off; off >>= 1) acc += __shfl_down(acc, off, 64);
    if (L == 0) wsum[w] = acc;
    __syncthreads();
    if (t == 0)
        atomicAdd(loss, (wsum[0] + wsum[1] + wsum[2] + wsum[3]) * (1.25f / (float)NELEM));
}

// ---------------------------------------------------------------------------
extern "C" void kernel_launch(void* const* d_in, const int* in_sizes, int n_in,
                              void* d_out, int out_size, void* d_ws, size_t ws_size,
                              hipStream_t stream) {
    const float* z  = (const float*)d_in[0];
    const float* cb = (const float*)d_in[1];
    float* out      = (float*)d_out;
    float* cn       = (float*)d_ws;                           // 4 KB
    unsigned* keys  = (unsigned*)((char*)d_ws + 4096);        // 2 x 128 KB
    uint2* cbf8     = (uint2*)((char*)d_ws + 4096 + 262144);  // 256 KB
    float* loss     = out + NELEM;

    hipMemsetAsync(loss, 0, sizeof(float), stream);
    prep_kernel<<<128, 256, 0, stream>>>(cb, cbf8, cn);
    vq_kernel<<<512, 256, 0, stream>>>(z, cbf8, cn, keys);
    scatter_kernel<<<512, 256, 0, stream>>>(z, cb, keys, out, loss);
}

// Round 7
// 119.382 us; speedup vs baseline: 3.7115x; 3.7115x over previous
//
#include <hip/hip_runtime.h>

// VQ: z [32,256,32,32] f32, codebook [1024,256] f32
// out: z_q [32,256,32,32] f32 (8388608) then loss scalar f32 (1)
#define NELEM 8388608

typedef __attribute__((ext_vector_type(4))) float f32x4;
typedef unsigned long long ull;

// ---------------------------------------------------------------------------
// prep: codebook -> fp8 e4m3 (scaled x256, exact pow2) in B-fragment-linear
// order for mfma_f32_16x16x32_fp8_fp8, plus exact fp32 norms cn[k], plus
// loss=0 (stream-ordered before scatter's atomicAdd).
// frag g = nt*8+ks (512 B): lane L holds cb[nt*16+(L&15)][ks*32+(L>>4)*8+0..7]
__global__ __launch_bounds__(256) void prep_kernel(const float* __restrict__ cb,
                                                   uint2* __restrict__ cbf8,
                                                   float* __restrict__ cn,
                                                   float* __restrict__ loss) {
    const int t = threadIdx.x;
    if (blockIdx.x == 0 && t == 0) *loss = 0.f;
    const int gt = blockIdx.x * 256 + t;          // 0..32767
    const int L = gt & 63, g = gt >> 6;           // frag 0..511
    const int nt = g >> 3, ks = g & 7;
    const int code = nt * 16 + (L & 15);
    const int k0 = ks * 32 + (L >> 4) * 8;
    const float* s = cb + code * 256 + k0;
    float v[8];
    #pragma unroll
    for (int j = 0; j < 8; ++j) v[j] = s[j] * 256.0f;
    int lo = 0, hi = 0;
    lo = __builtin_amdgcn_cvt_pk_fp8_f32(v[0], v[1], lo, false);
    lo = __builtin_amdgcn_cvt_pk_fp8_f32(v[2], v[3], lo, true);
    hi = __builtin_amdgcn_cvt_pk_fp8_f32(v[4], v[5], hi, false);
    hi = __builtin_amdgcn_cvt_pk_fp8_f32(v[6], v[7], hi, true);
    uint2 o; o.x = (unsigned)lo; o.y = (unsigned)hi;
    cbf8[g * 64 + L] = o;

    const int w = t >> 6, lane = t & 63;
    #pragma unroll
    for (int cc = 0; cc < 2; ++cc) {
        int cd = blockIdx.x * 8 + w * 2 + cc;
        float4 qv = *(const float4*)(cb + cd * 256 + lane * 4);
        float s2 = qv.x*qv.x + qv.y*qv.y + qv.z*qv.z + qv.w*qv.w;
        #pragma unroll
        for (int off = 32; off; off >>= 1) s2 += __shfl_down(s2, off, 64);
        if (lane == 0) cn[cd] = s2;
    }
}

// ---------------------------------------------------------------------------
// Argmin: grid 1024 = 512 pos-groups x 2 codebook halves (interleaved: pair
// on same XCD so the z tile re-read hits L2). Block 256 thr = 4 waves x 16
// pos = 64 pos, 512 codes. A in regs; B chunks (4 nt = 16 KB) double-buffered
// in LDS (34 KB total -> 4 blocks/CU). 16x16x32 fp8 MFMA.
// d = (cn[k]+1) - 2*dot > 0 => float bits monotone; key = (bits&~1023)|code.
// Each half writes its own keys slot (no atomics); scatter min-combines.
__global__ __launch_bounds__(256, 3) void vq_kernel(
        const float* __restrict__ z, const uint4* __restrict__ cbf8,
        const float* __restrict__ cn, unsigned* __restrict__ keys) {
    __shared__ float cnS[512];
    __shared__ uint4 Bs[2][1024];                 // 2 x 16 KB

    const int t = threadIdx.x, w = t >> 6, L = t & 63;
    const int col = L & 15, q = L >> 4;
    const int half = blockIdx.x & 1;
    const int pg = blockIdx.x >> 1;               // 0..511
    const int b = pg >> 4, hw0 = (pg & 15) << 6;

    // stage this half's cn (+1 bias for positivity/monotonicity)
    if (t < 128) *(float4*)&cnS[t * 4] = *(const float4*)(cn + half * 512 + t * 4);

    // B chunk 0 global loads (issue early, store after A phase)
    const uint4* bp = cbf8 + half * 8192;         // half's 256 frags x 32 uint4
    uint4 st0[4];
    #pragma unroll
    for (int i = 0; i < 4; ++i) st0[i] = bp[(i << 8) + t];

    // A-frags: wave w owns pos w*16..w*16+15. A[m][k=ks*32+q*8+j], x16 -> fp8
    ull af[8];
    const float* zb = z + ((size_t)b << 18) + hw0;
    {
        const float* zp = zb + (w * 16 + col) + ((q * 8) << 10);
        #pragma unroll
        for (int ks = 0; ks < 8; ++ks) {
            const float* sp = zp + ((ks * 32) << 10);
            float v[8];
            #pragma unroll
            for (int j = 0; j < 8; ++j) v[j] = sp[j << 10];
            int lo = 0, hi = 0;
            lo = __builtin_amdgcn_cvt_pk_fp8_f32(v[0]*16.f, v[1]*16.f, lo, false);
            lo = __builtin_amdgcn_cvt_pk_fp8_f32(v[2]*16.f, v[3]*16.f, lo, true);
            hi = __builtin_amdgcn_cvt_pk_fp8_f32(v[4]*16.f, v[5]*16.f, hi, false);
            hi = __builtin_amdgcn_cvt_pk_fp8_f32(v[6]*16.f, v[7]*16.f, hi, true);
            af[ks] = ((ull)(unsigned)hi << 32) | (unsigned)lo;
        }
    }

    #pragma unroll
    for (int i = 0; i < 4; ++i) Bs[0][(i << 8) + t] = st0[i];

    unsigned runmin[4];
    #pragma unroll
    for (int r = 0; r < 4; ++r) runmin[r] = 0xFFFFFFFFu;

    __syncthreads();

    const float SC = -4.8828125e-4f;   // -2 / (16*256)
    for (int it = 0; it < 8; ++it) {
        const int cur = it & 1;
        uint4 st2[4];
        if (it < 7) {
            #pragma unroll
            for (int i = 0; i < 4; ++i) st2[i] = bp[((it + 1) << 10) + (i << 8) + t];
        }
        const ull* bb = (const ull*)&Bs[cur][0];
        ull breg[4][8];
        #pragma unroll
        for (int n2 = 0; n2 < 4; ++n2)
            #pragma unroll
            for (int ks = 0; ks < 8; ++ks)
                breg[n2][ks] = bb[(n2 * 8 + ks) * 64 + L];

        f32x4 a0 = {0,0,0,0}, a1 = {0,0,0,0}, a2 = {0,0,0,0}, a3 = {0,0,0,0};
        #pragma unroll
        for (int ks = 0; ks < 8; ++ks) {            // 4 independent chains
            a0 = __builtin_amdgcn_mfma_f32_16x16x32_fp8_fp8((long long)af[ks], (long long)breg[0][ks], a0, 0, 0, 0);
            a1 = __builtin_amdgcn_mfma_f32_16x16x32_fp8_fp8((long long)af[ks], (long long)breg[1][ks], a1, 0, 0, 0);
            a2 = __builtin_amdgcn_mfma_f32_16x16x32_fp8_fp8((long long)af[ks], (long long)breg[2][ks], a2, 0, 0, 0);
            a3 = __builtin_amdgcn_mfma_f32_16x16x32_fp8_fp8((long long)af[ks], (long long)breg[3][ks], a3, 0, 0, 0);
        }
        const int ntb = it * 4;
        #pragma unroll
        for (int n2 = 0; n2 < 4; ++n2) {
            const f32x4& aa = (n2 == 0) ? a0 : (n2 == 1) ? a1 : (n2 == 2) ? a2 : a3;
            const float cnv = cnS[(ntb + n2) * 16 + col] + 1.0f;
            const unsigned kc = (unsigned)(half * 512 + (ntb + n2) * 16 + col);
            #pragma unroll
            for (int r = 0; r < 4; ++r) {
                float d = fmaf(SC, aa[r], cnv);             // ~[0.9, 1.1] > 0
                unsigned key = (__float_as_uint(d) & 0xFFFFFC00u) | kc;
                runmin[r] = min(runmin[r], key);
            }
        }
        if (it < 7) {
            #pragma unroll
            for (int i = 0; i < 4; ++i) Bs[cur ^ 1][(i << 8) + t] = st2[i];
        }
        __syncthreads();
    }

    // cross-lane min over the 16 code columns of this wave's tile
    #pragma unroll
    for (int r = 0; r < 4; ++r) {
        unsigned v = runmin[r];
        #pragma unroll
        for (int d = 1; d < 16; d <<= 1) v = min(v, (unsigned)__shfl_xor(v, d, 64));
        if (col == 0)
            keys[half * 32768 + pg * 64 + w * 16 + q * 4 + r] = v;
    }
}

// ---------------------------------------------------------------------------
// Scatter: combine halves, gather fp32 codebook rows (coalesced), transpose
// via LDS, write z_q; exact loss = 1.25*mean((q-z)^2).
__global__ __launch_bounds__(256) void scatter_kernel(
        const float* __restrict__ z, const float* __restrict__ cb,
        const unsigned* __restrict__ keys, float* __restrict__ out,
        float* __restrict__ loss) {
    __shared__ float Q[32][257];
    __shared__ int codeS[64];
    __shared__ float wsum[4];
    const int t = threadIdx.x, w = t >> 6, L = t & 63;
    const int n0 = blockIdx.x * 64;
    const int b = n0 >> 10, hw0 = n0 & 1023;

    if (t < 64) codeS[t] = (int)(min(keys[n0 + t], keys[32768 + n0 + t]) & 1023u);
    __syncthreads();

    float acc = 0.f;
    const size_t obase = ((size_t)b << 18) + hw0;
    const int pgq = L & 7, cidx = L >> 3;
    #pragma unroll
    for (int ch = 0; ch < 2; ++ch) {
        if (ch) __syncthreads();
        #pragma unroll
        for (int rr = 0; rr < 8; ++rr) {
            int row = w * 8 + rr;
            int code = codeS[ch * 32 + row];
            float4 v = *(const float4*)(cb + ((size_t)code << 8) + (L << 2));
            float* qp = &Q[row][L << 2];
            qp[0] = v.x; qp[1] = v.y; qp[2] = v.z; qp[3] = v.w;
        }
        __syncthreads();
        #pragma unroll
        for (int i = 0; i < 8; ++i) {
            int c = w * 64 + i * 8 + cidx;
            int p0 = pgq * 4;
            float4 qv;
            qv.x = Q[p0 + 0][c]; qv.y = Q[p0 + 1][c];
            qv.z = Q[p0 + 2][c]; qv.w = Q[p0 + 3][c];
            size_t addr = obase + ((size_t)c << 10) + ch * 32 + p0;
            float4 zv = *(const float4*)(z + addr);
            *(float4*)(out + addr) = qv;
            float dx = qv.x - zv.x, dy = qv.y - zv.y;
            float dz2 = qv.z - zv.z, dw = qv.w - zv.w;
            acc += dx * dx + dy * dy + dz2 * dz2 + dw * dw;
        }
    }
    #pragma unroll
    for (int off = 32; off; off >>= 1) acc += __shfl_down(acc, off, 64);
    if (L == 0) wsum[w] = acc;
    __syncthreads();
    if (t == 0)
        atomicAdd(loss, (wsum[0] + wsum[1] + wsum[2] + wsum[3]) * (1.25f / (float)NELEM));
}

// ---------------------------------------------------------------------------
extern "C" void kernel_launch(void* const* d_in, const int* in_sizes, int n_in,
                              void* d_out, int out_size, void* d_ws, size_t ws_size,
                              hipStream_t stream) {
    const float* z  = (const float*)d_in[0];
    const float* cb = (const float*)d_in[1];
    float* out      = (float*)d_out;
    float* cn       = (float*)d_ws;                           // 4 KB
    unsigned* keys  = (unsigned*)((char*)d_ws + 4096);        // 2 x 128 KB
    uint2* cbf8     = (uint2*)((char*)d_ws + 4096 + 262144);  // 256 KB
    float* loss     = out + NELEM;

    prep_kernel<<<128, 256, 0, stream>>>(cb, cbf8, cn, loss);
    vq_kernel<<<1024, 256, 0, stream>>>(z, (const uint4*)cbf8, cn, keys);
    scatter_kernel<<<512, 256, 0, stream>>>(z, cb, keys, out, loss);
}